// Round 6
// baseline (202.221 us; speedup 1.0000x reference)
//
#include <hip/hip_runtime.h>
#include <math.h>

typedef unsigned short u16;
typedef __attribute__((ext_vector_type(8))) short short8;    // 8 bf16 (4 VGPR)
typedef __attribute__((ext_vector_type(4))) float floatx4;
typedef __attribute__((ext_vector_type(4))) u16 v4u16;
typedef __attribute__((ext_vector_type(8))) u16 v8u16;

#define B_   16
#define C_   512
#define NSP  1024
#define EPSV 1e-5f
#define QSCALE 0.18033688011117f   // 0.125 * log2(e) — softmax in base 2

__device__ __forceinline__ u16 f2bf(float f) {
  union { float f; unsigned u; } v; v.f = f;
  unsigned r = v.u + 0x7FFFu + ((v.u >> 16) & 1u);   // RNE
  return (u16)(r >> 16);
}

__device__ __forceinline__ void gld16(const u16* g, u16* l) {
  __builtin_amdgcn_global_load_lds(
      (const __attribute__((address_space(1))) void*)g,
      (__attribute__((address_space(3))) void*)l, 16, 0, 0);
}

// inline-asm ds_read_b128: invisible to the compiler's alias analysis, so it
// is NOT ordered against outstanding global_load_lds (no implicit vmcnt(0)
// drain). "=&v" early-clobber: destination tuple must not alias any asm
// input address VGPR. Caller must ensure the target buffer has landed
// (explicit vmcnt/barrier protocol) and must follow the group with
// s_waitcnt lgkmcnt(0) + sched_barrier(0) before consuming (rule #18).
__device__ __forceinline__ short8 lds_read_b128(const u16* p) {
  short8 r;
  asm volatile("ds_read_b128 %0, %1"
               : "=&v"(r)
               : "v"((const __attribute__((address_space(3))) u16*)p));
  return r;
}

// pack hi16(a)|hi16(b)<<16 : bf16 truncation pack, 1 instr
__device__ __forceinline__ unsigned pk_bf(float a, float b) {
  return __builtin_amdgcn_perm(__float_as_uint(b), __float_as_uint(a), 0x07060302u);
}

// ------------- fp32 -> bf16 weight conversion (both weights, one launch) ----
__global__ __launch_bounds__(256) void cvt_bf16(
    const float* __restrict__ qa, u16* __restrict__ oa,     // 1536*512
    const float* __restrict__ pa, u16* __restrict__ ob)     // 512*512
{
  int blk = blockIdx.x;
  const float* in; u16* out; int i;
  if (blk < 768) { in = qa; out = oa; i = (blk * 256 + threadIdx.x) * 4; }
  else           { in = pa; out = ob; i = ((blk - 768) * 256 + threadIdx.x) * 4; }
  float4 v = *(const float4*)(in + i);
  v4u16 o = { f2bf(v.x), f2bf(v.y), f2bf(v.z), f2bf(v.w) };
  *(v4u16*)(out + i) = o;
}

// ------------- GroupNorm pass 1: partial sums, 8 blocks per (b,g) ----------
__global__ __launch_bounds__(256) void gn_stats(
    const float* __restrict__ x, float* __restrict__ stats)
{
  int blk = blockIdx.x;            // bg*8 + chunk
  int bg = blk >> 3, ck = blk & 7;
  const float4* xp = (const float4*)(x + (((size_t)bg * 64 + ck * 8) * NSP));
  float s = 0.f, ss = 0.f;
#pragma unroll
  for (int it = 0; it < 8; ++it) {
    float4 v = xp[it * 256 + threadIdx.x];
    s  += v.x + v.y + v.z + v.w;
    ss += v.x * v.x + v.y * v.y + v.z * v.z + v.w * v.w;
  }
  for (int off = 32; off > 0; off >>= 1) {
    s  += __shfl_down(s, off);
    ss += __shfl_down(ss, off);
  }
  __shared__ float rs[4], rss[4];
  int lane = threadIdx.x & 63, wv = threadIdx.x >> 6;
  if (lane == 0) { rs[wv] = s; rss[wv] = ss; }
  __syncthreads();
  if (threadIdx.x == 0) {
    float S  = rs[0] + rs[1] + rs[2] + rs[3];
    float SS = rss[0] + rss[1] + rss[2] + rss[3];
    atomicAdd(&stats[bg * 2], S);
    atomicAdd(&stats[bg * 2 + 1], SS);
  }
}

// ------------- GroupNorm pass 2: normalize + transpose to [b][n][c] -------
__global__ __launch_bounds__(256) void gn_apply(
    const float* __restrict__ x, const float* __restrict__ stats,
    const float* __restrict__ gw, const float* __restrict__ gb,
    u16* __restrict__ xn)
{
  int blk = blockIdx.x;            // bg*16 + nt
  int bg = blk >> 4, nt = blk & 15;
  int b = bg >> 3, g = bg & 7;
  float S = stats[bg * 2], SS = stats[bg * 2 + 1];
  float mu  = S * (1.f / 65536.f);
  float var = SS * (1.f / 65536.f) - mu * mu;
  float inv = rsqrtf(var + EPSV);
  __shared__ float T[64][65];
  const float* xb = x + (size_t)bg * 64 * NSP;
  int t = threadIdx.x;
#pragma unroll
  for (int it = 0; it < 4; ++it) {
    int task = it * 256 + t;
    int cc = task >> 4, ns = task & 15;
    float4 v = *(const float4*)(xb + (size_t)cc * NSP + nt * 64 + ns * 4);
    T[cc][ns * 4 + 0] = v.x; T[cc][ns * 4 + 1] = v.y;
    T[cc][ns * 4 + 2] = v.z; T[cc][ns * 4 + 3] = v.w;
  }
  __syncthreads();
#pragma unroll
  for (int it = 0; it < 2; ++it) {
    int task = it * 256 + t;
    int n = task >> 3, cs = task & 7;
    v8u16 o;
#pragma unroll
    for (int u = 0; u < 8; ++u) {
      int cg = g * 64 + cs * 8 + u;
      float val = (T[cs * 8 + u][n] - mu) * inv * gw[cg] + gb[cg];
      o[u] = f2bf(val);
    }
    *(v8u16*)(xn + ((size_t)b * NSP + nt * 64 + n) * C_ + g * 64 + cs * 8) = o;
  }
}

// ---- bf16 MFMA GEMM: C[b][m][n] = W[m][k] * X[b][n][k]^T + bias[m] ----
// Flat 1D grid, id = y*128 + b*8 + x -> m-tiles sharing an X-panel share id%8
// (same XCD -> B-panel L2-resident).
// v9 (kept from R5, validated): 3-stage counted-vmcnt pipeline + inline-asm
// ds_read_b128 frag loads (bypasses compiler's conservative vmcnt(0) drain
// after global_load_lds issue). Correctness held by explicit vmcnt(4)+
// s_barrier protocol; lgkmcnt(0)+sched_barrier(0) before MFMA (rule #18).
// MODE 0 (qkv): m<1024 -> out_qk[b][n][m] bf16 (Q rows scaled by QSCALE);
//               m>=1024 -> out_v[b][m-1024][n'] bf16, n' k-PERMUTED within
//               each 64-col group (k = (j&0x23)|((j&0x0C)<<1)|((j&0x10)>>2))
//               so attn PV A-frags are single ds_read_b128.
// MODE 1 (proj): out_f[b][m][n] fp32 = acc + bias + resid.
template <int MODE>
__global__ __launch_bounds__(256) void gemm_mfma(
    const u16* __restrict__ W, const u16* __restrict__ X,
    const float* __restrict__ bias, const float* __restrict__ resid,
    u16* __restrict__ out_qk, u16* __restrict__ out_v,
    float* __restrict__ out_f)
{
  __shared__ u16 smem[24576];      // 3 x 16KB stage buffers; epilogue overlays
  int id = blockIdx.x;
  int yb = id >> 7, rr = id & 127;
  int b = rr >> 3, xb_ = rr & 7;
  int m0 = yb * 128, n0 = xb_ * 128;
  int t = threadIdx.x, lane = t & 63, w = t >> 6;
  int c = lane & 15, q = lane >> 4;
  int wm = w >> 1, wn = w & 1;
  const u16* Xb = X + (size_t)b * NSP * C_;

  floatx4 acc[4][4];
#pragma unroll
  for (int mi = 0; mi < 4; ++mi)
#pragma unroll
    for (int ni = 0; ni < 4; ++ni) acc[mi][ni] = (floatx4){0.f, 0.f, 0.f, 0.f};

  auto stage = [&](int buf, int k0) {
    u16* Asb = smem + buf * 8192;
    u16* Bsb = Asb + 4096;
#pragma unroll
    for (int it = 0; it < 2; ++it) {
      int task = it * 256 + t;
      int mr = task >> 2;
      int gk = (task & 3) ^ ((mr >> 1) & 3);
      gld16(W + (size_t)(m0 + mr) * C_ + k0 + gk * 8, Asb + task * 8);
    }
#pragma unroll
    for (int it = 0; it < 2; ++it) {
      int task = it * 256 + t;
      int nr = task >> 2;
      int gk = (task & 3) ^ ((nr >> 1) & 3);
      gld16(Xb + (size_t)(n0 + nr) * C_ + k0 + gk * 8, Bsb + task * 8);
    }
  };

  auto compute = [&](int buf) {
    const u16* As = smem + buf * 8192;
    const u16* Bs = As + 4096;
    short8 af[4], bfr[4];
#pragma unroll
    for (int mi = 0; mi < 4; ++mi) {
      int m = wm * 64 + mi * 16 + c;
      af[mi] = lds_read_b128(As + m * 32 + ((q ^ ((m >> 1) & 3)) << 3));
    }
#pragma unroll
    for (int ni = 0; ni < 4; ++ni) {
      int n = wn * 64 + ni * 16 + c;
      bfr[ni] = lds_read_b128(Bs + n * 32 + ((q ^ ((n >> 1) & 3)) << 3));
    }
    asm volatile("s_waitcnt lgkmcnt(0)" ::: "memory");
    __builtin_amdgcn_sched_barrier(0);
#pragma unroll
    for (int mi = 0; mi < 4; ++mi)
#pragma unroll
      for (int ni = 0; ni < 4; ++ni)
        acc[mi][ni] = __builtin_amdgcn_mfma_f32_16x16x32_bf16(
            af[mi], bfr[ni], acc[mi][ni], 0, 0, 0);
  };

  stage(0, 0);
  stage(1, 32);
  int cur = 0, tgt = 2;
  for (int ki = 0; ki < 14; ++ki) {
    asm volatile("s_waitcnt vmcnt(4)" ::: "memory");
    __builtin_amdgcn_s_barrier();
    stage(tgt, (ki + 2) * 32);
    compute(cur);
    cur = (cur == 2) ? 0 : cur + 1;
    tgt = (tgt == 2) ? 0 : tgt + 1;
  }
  asm volatile("s_waitcnt vmcnt(4)" ::: "memory");
  __builtin_amdgcn_s_barrier();
  compute(2);                      // ki=14 -> buf 14%3 = 2
  asm volatile("s_waitcnt vmcnt(0)" ::: "memory");
  __builtin_amdgcn_s_barrier();
  compute(0);                      // ki=15 -> buf 15%3 = 0
  __syncthreads();                 // all waves out of buf0 before Cl overlay

  if (MODE == 0) {
    if (m0 < 1024) {       // Q/K region: transpose to [n][m] via LDS
      float sc = (m0 < 512) ? QSCALE : 1.0f;
      u16* Cl = smem;      // [128 n][136 m-stride]
#pragma unroll
      for (int mi = 0; mi < 4; ++mi) {
        floatx4 bi = *(const floatx4*)(bias + m0 + wm * 64 + mi * 16 + q * 4);
#pragma unroll
        for (int ni = 0; ni < 4; ++ni) {
          int n = wn * 64 + ni * 16 + c;
          int m = wm * 64 + mi * 16 + q * 4;
          v4u16 pk;
#pragma unroll
          for (int r = 0; r < 4; ++r) pk[r] = f2bf((acc[mi][ni][r] + bi[r]) * sc);
          *(v4u16*)(Cl + n * 136 + m) = pk;
        }
      }
      __syncthreads();
#pragma unroll
      for (int it = 0; it < 8; ++it) {
        int task = it * 256 + t;
        int n = task >> 4, seg = task & 15;
        v8u16 v = *(const v8u16*)(Cl + n * 136 + seg * 8);
        *(v8u16*)(out_qk + ((size_t)b * NSP + n0 + n) * 1024 + m0 + seg * 8) = v;
      }
    } else {               // V region: [m][n'] via LDS transpose, k-permuted
      u16* Cl = smem;      // [128 m][136 n-stride]
#pragma unroll
      for (int mi = 0; mi < 4; ++mi) {
        floatx4 bi = *(const floatx4*)(bias + m0 + wm * 64 + mi * 16 + q * 4);
#pragma unroll
        for (int ni = 0; ni < 4; ++ni) {
          int n = wn * 64 + ni * 16 + c;
          int m = wm * 64 + mi * 16 + q * 4;
#pragma unroll
          for (int r = 0; r < 4; ++r)
            Cl[(m + r) * 136 + n] = f2bf(acc[mi][ni][r] + bi[r]);
        }
      }
      __syncthreads();
      // store with per-64-group column permutation j -> k:
      // k = (j&0x23) | ((j&0x0C)<<1) | ((j&0x10)>>2).
      // source octet seg*8..+7 maps to two 4-runs at k0 and k0+8,
      // k0 = ((s&4)<<3) | ((s&1)<<4) | ((s&2)<<1), s = seg&7.
#pragma unroll
      for (int it = 0; it < 8; ++it) {
        int task = it * 256 + t;
        int m = task >> 4, seg = task & 15;
        int g64 = seg >> 3, s = seg & 7;
        int k0 = ((s & 4) << 3) | ((s & 1) << 4) | ((s & 2) << 1);
        v8u16 v = *(const v8u16*)(Cl + m * 136 + seg * 8);
        v4u16 lo = { v[0], v[1], v[2], v[3] };
        v4u16 hi = { v[4], v[5], v[6], v[7] };
        size_t base = ((size_t)b * C_ + m0 - 1024 + m) * NSP + n0 + g64 * 64;
        *(v4u16*)(out_v + base + k0) = lo;
        *(v4u16*)(out_v + base + k0 + 8) = hi;
      }
    }
  } else {                 // proj: fp32 [m][n] + bias + residual
#pragma unroll
    for (int mi = 0; mi < 4; ++mi) {
      floatx4 bi = *(const floatx4*)(bias + m0 + wm * 64 + mi * 16 + q * 4);
#pragma unroll
      for (int ni = 0; ni < 4; ++ni) {
        int n = n0 + wn * 64 + ni * 16 + c;
        int m = m0 + wm * 64 + mi * 16 + q * 4;
#pragma unroll
        for (int r = 0; r < 4; ++r) {
          size_t o = ((size_t)b * C_ + m + r) * NSP + n;
          out_f[o] = acc[mi][ni][r] + bi[r] + resid[o];
        }
      }
    }
  }
}

// ---- flash attention v8: 8 waves x 16 q-rows (wave-parallelism 2x) ----
// Work id = i0*128 + (h*16+b) (XCD swizzle). 512 threads, 8 waves; each wave
// owns 16 q-rows and processes ALL 64 j per iter tile -> no cross-wave merge.
// Same total MFMA/VALU as v7, but per-wave serial chain (QK->exp->PV) is
// half as long and waves/SIMD doubles -> one wave's exp/pack overlaps
// another's MFMA cluster (m114 co-scheduling). R5 showed MFMA 45% + VALU
// 40% of wall with only ~2 waves/SIMD resident — overlap-limited.
// LDS 32KB: Q [0..8192) u16 (dead after frag load -> odd-parity K/V),
// even-parity K/V at [8192..16384) u16. Softmax base-2 (Q pre-scaled).
//  - asm ds_read_b128 frag reads batched under one lgkmcnt(0)+sched_barrier
//  - softmax denominator via mfma(ones, P) on the matrix pipe
//  - V k-permuted by gemm0 -> PV A-frag is ONE ds_read_b128
//  - s_setprio(1) around the PV MFMA cluster (T5)
__global__ __launch_bounds__(512, 4) void attn_mfma(
    const u16* __restrict__ qk, const u16* __restrict__ vbuf,
    u16* __restrict__ att)
{
  __shared__ u16 __align__(16) smem[16384];   // 32 KB
  int id = blockIdx.x;
  int hb = id & 127;
  int i0 = id >> 7;
  int h = hb >> 4, b = hb & 15;
  int t = threadIdx.x, lane = t & 63, w = t >> 6;   // w in 0..7
  int c = lane & 15, q = lane >> 4;
  const u16* qbase = qk + (size_t)b * NSP * 1024;
  const u16* vbase = vbuf + (size_t)(b * C_ + h * 64) * NSP;

  // stage Q(128x64) -> [0..8192); K0 -> [8192..12288); V0 -> [12288..16384)
#pragma unroll
  for (int it = 0; it < 2; ++it) {
    int task = it * 512 + t;
    int r = task >> 3, seg = task & 7, ds = (seg ^ (r & 7)) * 8;
    gld16(qbase + (size_t)(i0 * 128 + r) * 1024 + h * 64 + ds, smem + task * 8);
  }
  {
    int r = t >> 3, seg = t & 7, ds = (seg ^ (r & 7)) * 8;
    gld16(qbase + (size_t)r * 1024 + 512 + h * 64 + ds, smem + 8192 + t * 8);
    gld16(vbase + (size_t)r * NSP + ds, smem + 12288 + t * 8);
  }
  __syncthreads();

  short8 qa[2];                    // rows w*16 + c, two 8-elem k-chunks
  {
    int row = w * 16 + c;
#pragma unroll
    for (int ch = 0; ch < 2; ++ch)
      qa[ch] = *(const short8*)(smem + row * 64 + (((q + 4 * ch) ^ (c & 7)) << 3));
  }
  __syncthreads();                 // all waves done reading Q before overlay

  short8 onesf;                    // all-ones bf16 A-operand (1.0 = 0x3F80)
#pragma unroll
  for (int u = 0; u < 8; ++u) onesf[u] = (short)0x3F80;

  floatx4 Oacc[4];                 // [dt] for this wave's 16 q-rows
  floatx4 OaccT;                   // ones-MFMA column sums -> denominator
#pragma unroll
  for (int dt = 0; dt < 4; ++dt) Oacc[dt] = (floatx4){0.f, 0.f, 0.f, 0.f};
  OaccT = (floatx4){0.f, 0.f, 0.f, 0.f};

  for (int j0 = 0; j0 < 16; ++j0) {
    int p = j0 & 1;
    u16* KS = smem + (p ? 0 : 8192);
    u16* VS = KS + 4096;
    if (j0 < 15) {                 // prefetch next K/V into the other parity
      u16* KN = smem + (p ? 8192 : 0);
      u16* VN = KN + 4096;
      int r = t >> 3, seg = t & 7, ds = (seg ^ (r & 7)) * 8;
      gld16(qbase + (size_t)((j0 + 1) * 64 + r) * 1024 + 512 + h * 64 + ds,
            KN + t * 8);
      gld16(vbase + (size_t)r * NSP + (j0 + 1) * 64 + ds, VN + t * 8);
    }
#pragma unroll
    for (int jt2 = 0; jt2 < 2; ++jt2) {
      // --- batched asm frag reads: 4x K + 4x V, one lgkm wait ---
      short8 kb[2][2], vf[4];
#pragma unroll
      for (int jj = 0; jj < 2; ++jj) {
        int row = (jt2 * 2 + jj) * 16 + c;
        kb[jj][0] = lds_read_b128(KS + row * 64 + ((q ^ (row & 7)) << 3));
        kb[jj][1] = lds_read_b128(KS + row * 64 + (((q + 4) ^ (row & 7)) << 3));
      }
#pragma unroll
      for (int dt = 0; dt < 4; ++dt) {
        int dd = dt * 16 + c;
        vf[dt] = lds_read_b128(VS + dd * 64 + (((jt2 * 4 + q) ^ (dd & 7)) << 3));
      }
      asm volatile("s_waitcnt lgkmcnt(0)" ::: "memory");
      __builtin_amdgcn_sched_barrier(0);
      // --- QK half: S^T = K·Q^T for 32 j x 16 q, base-2 exp, pack bf16 ---
      unsigned pk2[2][2];
#pragma unroll
      for (int jj = 0; jj < 2; ++jj) {
        floatx4 z = (floatx4){0.f, 0.f, 0.f, 0.f};
        z = __builtin_amdgcn_mfma_f32_16x16x32_bf16(kb[jj][0], qa[0], z, 0, 0, 0);
        z = __builtin_amdgcn_mfma_f32_16x16x32_bf16(kb[jj][1], qa[1], z, 0, 0, 0);
        float p0 = __builtin_amdgcn_exp2f(z[0]);
        float p1 = __builtin_amdgcn_exp2f(z[1]);
        float p2 = __builtin_amdgcn_exp2f(z[2]);
        float p3 = __builtin_amdgcn_exp2f(z[3]);
        pk2[jj][0] = pk_bf(p0, p1);
        pk2[jj][1] = pk_bf(p2, p3);
      }
      short8 pf;
      {
        union { short8 s; unsigned d[4]; } u;
        u.d[0] = pk2[0][0]; u.d[1] = pk2[0][1];
        u.d[2] = pk2[1][0]; u.d[3] = pk2[1][1];
        pf = u.s;
      }
      // --- PV half: k-permuted V, all operands already in regs ---
      __builtin_amdgcn_s_setprio(1);
#pragma unroll
      for (int dt = 0; dt < 4; ++dt)
        Oacc[dt] = __builtin_amdgcn_mfma_f32_16x16x32_bf16(
            vf[dt], pf, Oacc[dt], 0, 0, 0);
      OaccT = __builtin_amdgcn_mfma_f32_16x16x32_bf16(onesf, pf, OaccT, 0, 0, 0);
      __builtin_amdgcn_s_setprio(0);
    }
    __syncthreads();
  }

  // ---- epilogue: denominator straight from ones-MFMA rows (all equal) ----
  {
    float rinv = 1.f / OaccT[0];
    int n = i0 * 128 + w * 16 + c;
#pragma unroll
    for (int dt = 0; dt < 4; ++dt) {
      v4u16 pk;
#pragma unroll
      for (int r = 0; r < 4; ++r) pk[r] = f2bf(Oacc[dt][r] * rinv);
      *(v4u16*)(att + ((size_t)b * NSP + n) * C_ + h * 64 + dt * 16 + q * 4) = pk;
    }
  }
}

extern "C" void kernel_launch(void* const* d_in, const int* in_sizes, int n_in,
                              void* d_out, int out_size, void* d_ws, size_t ws_size,
                              hipStream_t stream)
{
  const float* x    = (const float*)d_in[0];
  const float* gw   = (const float*)d_in[1];
  const float* gb   = (const float*)d_in[2];
  const float* qkvw = (const float*)d_in[3];
  const float* qkvb = (const float*)d_in[4];
  const float* pw   = (const float*)d_in[5];
  const float* pb   = (const float*)d_in[6];
  float* out = (float*)d_out;

  u16* xn    = (u16*)d_ws;             // [b][n][c]
  u16* qkb   = xn   + 8388608;         // [b][n][1024]
  u16* vbf   = qkb  + 16777216;        // [b][dd][n'] (k-permuted 64-groups)
  u16* attb  = vbf  + 8388608;         // [b][n][c]
  u16* wq    = attb + 8388608;         // [1536][512]
  u16* wp    = wq   + 786432;          // [512][512]
  float* stats = (float*)(wp + 262144);  // [128][2] fp32

  hipMemsetAsync(stats, 0, 128 * 2 * sizeof(float), stream);
  cvt_bf16<<<1024, 256, 0, stream>>>(qkvw, wq, pw, wp);
  gn_stats<<<1024, 256, 0, stream>>>(x, stats);
  gn_apply<<<2048, 256, 0, stream>>>(x, stats, gw, gb, xn);
  gemm_mfma<0><<<dim3(1536), 256, 0, stream>>>(
      wq, xn, qkvb, nullptr, qkb, vbf, nullptr);
  attn_mfma<<<dim3(1024), 512, 0, stream>>>(qkb, vbf, attb);
  gemm_mfma<1><<<dim3(512), 256, 0, stream>>>(
      wp, attb, pb, x, nullptr, nullptr, out);
}

// Round 7
// 198.222 us; speedup vs baseline: 1.0202x; 1.0202x over previous
//
#include <hip/hip_runtime.h>
#include <math.h>

typedef unsigned short u16;
typedef __attribute__((ext_vector_type(8))) short short8;    // 8 bf16 (4 VGPR)
typedef __attribute__((ext_vector_type(4))) float floatx4;
typedef __attribute__((ext_vector_type(4))) u16 v4u16;
typedef __attribute__((ext_vector_type(8))) u16 v8u16;

#define B_   16
#define C_   512
#define NSP  1024
#define EPSV 1e-5f
#define QSCALE 0.18033688011117f   // 0.125 * log2(e) — softmax in base 2

__device__ __forceinline__ u16 f2bf(float f) {
  union { float f; unsigned u; } v; v.f = f;
  unsigned r = v.u + 0x7FFFu + ((v.u >> 16) & 1u);   // RNE
  return (u16)(r >> 16);
}

__device__ __forceinline__ void gld16(const u16* g, u16* l) {
  __builtin_amdgcn_global_load_lds(
      (const __attribute__((address_space(1))) void*)g,
      (__attribute__((address_space(3))) void*)l, 16, 0, 0);
}

// inline-asm ds_read_b128: invisible to the compiler's alias analysis, so it
// is NOT ordered against outstanding global_load_lds (no implicit vmcnt(0)
// drain). "=&v" early-clobber: destination tuple must not alias any asm
// input address VGPR. Caller must ensure the target buffer has landed
// (explicit vmcnt/barrier protocol) and must follow the group with
// s_waitcnt lgkmcnt(0) + sched_barrier(0) before consuming (rule #18).
__device__ __forceinline__ short8 lds_read_b128(const u16* p) {
  short8 r;
  asm volatile("ds_read_b128 %0, %1"
               : "=&v"(r)
               : "v"((const __attribute__((address_space(3))) u16*)p));
  return r;
}

// pack hi16(a)|hi16(b)<<16 : bf16 truncation pack, 1 instr
__device__ __forceinline__ unsigned pk_bf(float a, float b) {
  return __builtin_amdgcn_perm(__float_as_uint(b), __float_as_uint(a), 0x07060302u);
}

// ------------- fp32 -> bf16 weight conversion (both weights, one launch) ----
__global__ __launch_bounds__(256) void cvt_bf16(
    const float* __restrict__ qa, u16* __restrict__ oa,     // 1536*512
    const float* __restrict__ pa, u16* __restrict__ ob)     // 512*512
{
  int blk = blockIdx.x;
  const float* in; u16* out; int i;
  if (blk < 768) { in = qa; out = oa; i = (blk * 256 + threadIdx.x) * 4; }
  else           { in = pa; out = ob; i = ((blk - 768) * 256 + threadIdx.x) * 4; }
  float4 v = *(const float4*)(in + i);
  v4u16 o = { f2bf(v.x), f2bf(v.y), f2bf(v.z), f2bf(v.w) };
  *(v4u16*)(out + i) = o;
}

// ------------- GroupNorm pass 1: partial sums, 8 blocks per (b,g) ----------
__global__ __launch_bounds__(256) void gn_stats(
    const float* __restrict__ x, float* __restrict__ stats)
{
  int blk = blockIdx.x;            // bg*8 + chunk
  int bg = blk >> 3, ck = blk & 7;
  const float4* xp = (const float4*)(x + (((size_t)bg * 64 + ck * 8) * NSP));
  float s = 0.f, ss = 0.f;
#pragma unroll
  for (int it = 0; it < 8; ++it) {
    float4 v = xp[it * 256 + threadIdx.x];
    s  += v.x + v.y + v.z + v.w;
    ss += v.x * v.x + v.y * v.y + v.z * v.z + v.w * v.w;
  }
  for (int off = 32; off > 0; off >>= 1) {
    s  += __shfl_down(s, off);
    ss += __shfl_down(ss, off);
  }
  __shared__ float rs[4], rss[4];
  int lane = threadIdx.x & 63, wv = threadIdx.x >> 6;
  if (lane == 0) { rs[wv] = s; rss[wv] = ss; }
  __syncthreads();
  if (threadIdx.x == 0) {
    float S  = rs[0] + rs[1] + rs[2] + rs[3];
    float SS = rss[0] + rss[1] + rss[2] + rss[3];
    atomicAdd(&stats[bg * 2], S);
    atomicAdd(&stats[bg * 2 + 1], SS);
  }
}

// ------------- GroupNorm pass 2: normalize + transpose to [b][n][c] -------
__global__ __launch_bounds__(256) void gn_apply(
    const float* __restrict__ x, const float* __restrict__ stats,
    const float* __restrict__ gw, const float* __restrict__ gb,
    u16* __restrict__ xn)
{
  int blk = blockIdx.x;            // bg*16 + nt
  int bg = blk >> 4, nt = blk & 15;
  int b = bg >> 3, g = bg & 7;
  float S = stats[bg * 2], SS = stats[bg * 2 + 1];
  float mu  = S * (1.f / 65536.f);
  float var = SS * (1.f / 65536.f) - mu * mu;
  float inv = rsqrtf(var + EPSV);
  __shared__ float T[64][65];
  const float* xb = x + (size_t)bg * 64 * NSP;
  int t = threadIdx.x;
#pragma unroll
  for (int it = 0; it < 4; ++it) {
    int task = it * 256 + t;
    int cc = task >> 4, ns = task & 15;
    float4 v = *(const float4*)(xb + (size_t)cc * NSP + nt * 64 + ns * 4);
    T[cc][ns * 4 + 0] = v.x; T[cc][ns * 4 + 1] = v.y;
    T[cc][ns * 4 + 2] = v.z; T[cc][ns * 4 + 3] = v.w;
  }
  __syncthreads();
#pragma unroll
  for (int it = 0; it < 2; ++it) {
    int task = it * 256 + t;
    int n = task >> 3, cs = task & 7;
    v8u16 o;
#pragma unroll
    for (int u = 0; u < 8; ++u) {
      int cg = g * 64 + cs * 8 + u;
      float val = (T[cs * 8 + u][n] - mu) * inv * gw[cg] + gb[cg];
      o[u] = f2bf(val);
    }
    *(v8u16*)(xn + ((size_t)b * NSP + nt * 64 + n) * C_ + g * 64 + cs * 8) = o;
  }
}

// ---- bf16 MFMA GEMM: C[b][m][n] = W[m][k] * X[b][n][k]^T + bias[m] ----
// Flat 1D grid, id = y*128 + b*8 + x -> m-tiles sharing an X-panel share id%8
// (same XCD -> B-panel L2-resident).
// v9 (kept from R5, validated): 3-stage counted-vmcnt pipeline + inline-asm
// ds_read_b128 frag loads (bypasses compiler's conservative vmcnt(0) drain
// after global_load_lds issue). Correctness held by explicit vmcnt(4)+
// s_barrier protocol; lgkmcnt(0)+sched_barrier(0) before MFMA (rule #18).
// MODE 0 (qkv): m<1024 -> out_qk[b][n][m] bf16 (Q rows scaled by QSCALE);
//               m>=1024 -> out_v[b][m-1024][n'] bf16, n' k-PERMUTED within
//               each 64-col group (k = (j&0x23)|((j&0x0C)<<1)|((j&0x10)>>2))
//               so attn PV A-frags are single ds_read_b128.
// MODE 1 (proj): out_f[b][m][n] fp32 = acc + bias + resid.
template <int MODE>
__global__ __launch_bounds__(256) void gemm_mfma(
    const u16* __restrict__ W, const u16* __restrict__ X,
    const float* __restrict__ bias, const float* __restrict__ resid,
    u16* __restrict__ out_qk, u16* __restrict__ out_v,
    float* __restrict__ out_f)
{
  __shared__ u16 smem[24576];      // 3 x 16KB stage buffers; epilogue overlays
  int id = blockIdx.x;
  int yb = id >> 7, rr = id & 127;
  int b = rr >> 3, xb_ = rr & 7;
  int m0 = yb * 128, n0 = xb_ * 128;
  int t = threadIdx.x, lane = t & 63, w = t >> 6;
  int c = lane & 15, q = lane >> 4;
  int wm = w >> 1, wn = w & 1;
  const u16* Xb = X + (size_t)b * NSP * C_;

  floatx4 acc[4][4];
#pragma unroll
  for (int mi = 0; mi < 4; ++mi)
#pragma unroll
    for (int ni = 0; ni < 4; ++ni) acc[mi][ni] = (floatx4){0.f, 0.f, 0.f, 0.f};

  auto stage = [&](int buf, int k0) {
    u16* Asb = smem + buf * 8192;
    u16* Bsb = Asb + 4096;
#pragma unroll
    for (int it = 0; it < 2; ++it) {
      int task = it * 256 + t;
      int mr = task >> 2;
      int gk = (task & 3) ^ ((mr >> 1) & 3);
      gld16(W + (size_t)(m0 + mr) * C_ + k0 + gk * 8, Asb + task * 8);
    }
#pragma unroll
    for (int it = 0; it < 2; ++it) {
      int task = it * 256 + t;
      int nr = task >> 2;
      int gk = (task & 3) ^ ((nr >> 1) & 3);
      gld16(Xb + (size_t)(n0 + nr) * C_ + k0 + gk * 8, Bsb + task * 8);
    }
  };

  auto compute = [&](int buf) {
    const u16* As = smem + buf * 8192;
    const u16* Bs = As + 4096;
    short8 af[4], bfr[4];
#pragma unroll
    for (int mi = 0; mi < 4; ++mi) {
      int m = wm * 64 + mi * 16 + c;
      af[mi] = lds_read_b128(As + m * 32 + ((q ^ ((m >> 1) & 3)) << 3));
    }
#pragma unroll
    for (int ni = 0; ni < 4; ++ni) {
      int n = wn * 64 + ni * 16 + c;
      bfr[ni] = lds_read_b128(Bs + n * 32 + ((q ^ ((n >> 1) & 3)) << 3));
    }
    asm volatile("s_waitcnt lgkmcnt(0)" ::: "memory");
    __builtin_amdgcn_sched_barrier(0);
#pragma unroll
    for (int mi = 0; mi < 4; ++mi)
#pragma unroll
      for (int ni = 0; ni < 4; ++ni)
        acc[mi][ni] = __builtin_amdgcn_mfma_f32_16x16x32_bf16(
            af[mi], bfr[ni], acc[mi][ni], 0, 0, 0);
  };

  stage(0, 0);
  stage(1, 32);
  int cur = 0, tgt = 2;
  for (int ki = 0; ki < 14; ++ki) {
    asm volatile("s_waitcnt vmcnt(4)" ::: "memory");
    __builtin_amdgcn_s_barrier();
    stage(tgt, (ki + 2) * 32);
    compute(cur);
    cur = (cur == 2) ? 0 : cur + 1;
    tgt = (tgt == 2) ? 0 : tgt + 1;
  }
  asm volatile("s_waitcnt vmcnt(4)" ::: "memory");
  __builtin_amdgcn_s_barrier();
  compute(2);                      // ki=14 -> buf 14%3 = 2
  asm volatile("s_waitcnt vmcnt(0)" ::: "memory");
  __builtin_amdgcn_s_barrier();
  compute(0);                      // ki=15 -> buf 15%3 = 0
  __syncthreads();                 // all waves out of buf0 before Cl overlay

  if (MODE == 0) {
    if (m0 < 1024) {       // Q/K region: transpose to [n][m] via LDS
      float sc = (m0 < 512) ? QSCALE : 1.0f;
      u16* Cl = smem;      // [128 n][136 m-stride]
#pragma unroll
      for (int mi = 0; mi < 4; ++mi) {
        floatx4 bi = *(const floatx4*)(bias + m0 + wm * 64 + mi * 16 + q * 4);
#pragma unroll
        for (int ni = 0; ni < 4; ++ni) {
          int n = wn * 64 + ni * 16 + c;
          int m = wm * 64 + mi * 16 + q * 4;
          v4u16 pk;
#pragma unroll
          for (int r = 0; r < 4; ++r) pk[r] = f2bf((acc[mi][ni][r] + bi[r]) * sc);
          *(v4u16*)(Cl + n * 136 + m) = pk;
        }
      }
      __syncthreads();
#pragma unroll
      for (int it = 0; it < 8; ++it) {
        int task = it * 256 + t;
        int n = task >> 4, seg = task & 15;
        v8u16 v = *(const v8u16*)(Cl + n * 136 + seg * 8);
        *(v8u16*)(out_qk + ((size_t)b * NSP + n0 + n) * 1024 + m0 + seg * 8) = v;
      }
    } else {               // V region: [m][n'] via LDS transpose, k-permuted
      u16* Cl = smem;      // [128 m][136 n-stride]
#pragma unroll
      for (int mi = 0; mi < 4; ++mi) {
        floatx4 bi = *(const floatx4*)(bias + m0 + wm * 64 + mi * 16 + q * 4);
#pragma unroll
        for (int ni = 0; ni < 4; ++ni) {
          int n = wn * 64 + ni * 16 + c;
          int m = wm * 64 + mi * 16 + q * 4;
#pragma unroll
          for (int r = 0; r < 4; ++r)
            Cl[(m + r) * 136 + n] = f2bf(acc[mi][ni][r] + bi[r]);
        }
      }
      __syncthreads();
      // store with per-64-group column permutation j -> k:
      // k = (j&0x23) | ((j&0x0C)<<1) | ((j&0x10)>>2).
      // source octet seg*8..+7 maps to two 4-runs at k0 and k0+8,
      // k0 = ((s&4)<<3) | ((s&1)<<4) | ((s&2)<<1), s = seg&7.
#pragma unroll
      for (int it = 0; it < 8; ++it) {
        int task = it * 256 + t;
        int m = task >> 4, seg = task & 15;
        int g64 = seg >> 3, s = seg & 7;
        int k0 = ((s & 4) << 3) | ((s & 1) << 4) | ((s & 2) << 1);
        v8u16 v = *(const v8u16*)(Cl + m * 136 + seg * 8);
        v4u16 lo = { v[0], v[1], v[2], v[3] };
        v4u16 hi = { v[4], v[5], v[6], v[7] };
        size_t base = ((size_t)b * C_ + m0 - 1024 + m) * NSP + n0 + g64 * 64;
        *(v4u16*)(out_v + base + k0) = lo;
        *(v4u16*)(out_v + base + k0 + 8) = hi;
      }
    }
  } else {                 // proj: fp32 [m][n] + bias + residual
#pragma unroll
    for (int mi = 0; mi < 4; ++mi) {
      floatx4 bi = *(const floatx4*)(bias + m0 + wm * 64 + mi * 16 + q * 4);
#pragma unroll
      for (int ni = 0; ni < 4; ++ni) {
        int n = n0 + wn * 64 + ni * 16 + c;
        int m = m0 + wm * 64 + mi * 16 + q * 4;
#pragma unroll
        for (int r = 0; r < 4; ++r) {
          size_t o = ((size_t)b * C_ + m + r) * NSP + n;
          out_f[o] = acc[mi][ni][r] + bi[r] + resid[o];
        }
      }
    }
  }
}

// ---- flash attention v9: 4 waves + one-step software pipeline (T15) ----
// R6 post-mortem: 8-wave TLP made it WORSE (43.2 vs 41.0) — limiter is the
// within-wave chain QK->exp->PV, not residency. v9 breaks the chain: keep
// P/V fragments of step s-1 in registers; at step s issue {8 asm ds_reads}
// -> PV(prev) cluster (register-only MFMA, runs under the ds_read latency
// AND overlaps next exp on the trans pipe) -> lgkmcnt(0)+sched_barrier ->
// QK(cur) -> exp/pack (becomes prev). Ping-pong names via vf2[jt2]/[jt2^1]
// (jt2 unrolled -> static indices, rule #20). First-step PV uses zeroed
// pf AND vf (avoid 0*NaN); final PV cluster after the loop.
// LDS 32KB: Q [0..8192) (dead after frag load -> odd-parity K/V buffer),
// even-parity K/V at [8192..16384). Softmax base-2 (Q pre-scaled in gemm0).
// Denominator via mfma(ones, P). V k-permuted by gemm0 -> single b128 frag.
// launch_bounds(256,3): live state ~150 VGPR; the (256,4) cap of 128 would
// spill.
__global__ __launch_bounds__(256, 3) void attn_mfma(
    const u16* __restrict__ qk, const u16* __restrict__ vbuf,
    u16* __restrict__ att)
{
  __shared__ u16 __align__(16) smem[16384];   // 32 KB
  int id = blockIdx.x;
  int hb = id & 127;
  int i0 = id >> 7;
  int h = hb >> 4, b = hb & 15;
  int t = threadIdx.x, lane = t & 63, w = t >> 6;
  int c = lane & 15, q = lane >> 4;
  const u16* qbase = qk + (size_t)b * NSP * 1024;
  const u16* vbase = vbuf + (size_t)(b * C_ + h * 64) * NSP;

  // stage Q(128x64) -> [0..8192); K0 -> [8192..12288); V0 -> [12288..16384)
#pragma unroll
  for (int it = 0; it < 4; ++it) {
    int task = it * 256 + t;
    int r = task >> 3, seg = task & 7, ds = (seg ^ (r & 7)) * 8;
    gld16(qbase + (size_t)(i0 * 128 + r) * 1024 + h * 64 + ds, smem + task * 8);
  }
#pragma unroll
  for (int it = 0; it < 2; ++it) {
    int task = it * 256 + t;
    int r = task >> 3, seg = task & 7, ds = (seg ^ (r & 7)) * 8;
    gld16(qbase + (size_t)r * 1024 + 512 + h * 64 + ds, smem + 8192 + task * 8);
    gld16(vbase + (size_t)r * NSP + ds, smem + 12288 + task * 8);
  }
  __syncthreads();

  short8 qa[2][2];                 // rows w*32 + nf*16 + c
#pragma unroll
  for (int nf = 0; nf < 2; ++nf) {
    int row = w * 32 + nf * 16 + c;
#pragma unroll
    for (int ch = 0; ch < 2; ++ch)
      qa[nf][ch] = *(const short8*)(smem + row * 64 + (((q + 4 * ch) ^ (c & 7)) << 3));
  }
  __syncthreads();                 // all waves done reading Q before overlay

  short8 onesf;                    // all-ones bf16 A-operand (1.0 = 0x3F80)
#pragma unroll
  for (int u = 0; u < 8; ++u) onesf[u] = (short)0x3F80;

  floatx4 Oacc[4][2];              // [dt][nf]
  floatx4 OaccT[2];                // ones-MFMA column sums -> denominator
#pragma unroll
  for (int dt = 0; dt < 4; ++dt)
#pragma unroll
    for (int nf = 0; nf < 2; ++nf) Oacc[dt][nf] = (floatx4){0.f, 0.f, 0.f, 0.f};
#pragma unroll
  for (int nf = 0; nf < 2; ++nf) OaccT[nf] = (floatx4){0.f, 0.f, 0.f, 0.f};

  // pipeline state: index 1 is "prev" for the first step of each j0
  short8 vf2[2][4], pf2[2][2];
#pragma unroll
  for (int i = 0; i < 4; ++i)
    vf2[1][i] = (short8){0, 0, 0, 0, 0, 0, 0, 0};
#pragma unroll
  for (int i = 0; i < 2; ++i)
    pf2[1][i] = (short8){0, 0, 0, 0, 0, 0, 0, 0};

  for (int j0 = 0; j0 < 16; ++j0) {
    int p = j0 & 1;
    u16* KS = smem + (p ? 0 : 8192);
    u16* VS = KS + 4096;
    if (j0 < 15) {                 // prefetch next K/V into the other parity
      u16* KN = smem + (p ? 8192 : 0);
      u16* VN = KN + 4096;
#pragma unroll
      for (int it = 0; it < 2; ++it) {
        int task = it * 256 + t;
        int r = task >> 3, seg = task & 7, ds = (seg ^ (r & 7)) * 8;
        gld16(qbase + (size_t)((j0 + 1) * 64 + r) * 1024 + 512 + h * 64 + ds,
              KN + task * 8);
        gld16(vbase + (size_t)r * NSP + (j0 + 1) * 64 + ds, VN + task * 8);
      }
    }
#pragma unroll
    for (int jt2 = 0; jt2 < 2; ++jt2) {
      short8 (&vfc)[4] = vf2[jt2];       // cur (written this step)
      short8 (&vfp)[4] = vf2[jt2 ^ 1];   // prev (consumed this step)
      short8 (&pfc)[2] = pf2[jt2];
      short8 (&pfp)[2] = pf2[jt2 ^ 1];
      // --- 1. issue 8 asm ds_reads (4 K + 4 V cur) ---
      short8 kb[2][2];
#pragma unroll
      for (int jj = 0; jj < 2; ++jj) {
        int row = (jt2 * 2 + jj) * 16 + c;
        kb[jj][0] = lds_read_b128(KS + row * 64 + ((q ^ (row & 7)) << 3));
        kb[jj][1] = lds_read_b128(KS + row * 64 + (((q + 4) ^ (row & 7)) << 3));
      }
#pragma unroll
      for (int dt = 0; dt < 4; ++dt) {
        int dd = dt * 16 + c;
        vfc[dt] = lds_read_b128(VS + dd * 64 + (((jt2 * 4 + q) ^ (dd & 7)) << 3));
      }
      __builtin_amdgcn_sched_barrier(0);
      // --- 2. PV(prev): register-only MFMA, overlaps ds_read latency ---
      __builtin_amdgcn_s_setprio(1);
#pragma unroll
      for (int dt = 0; dt < 4; ++dt)
#pragma unroll
        for (int nf = 0; nf < 2; ++nf)
          Oacc[dt][nf] = __builtin_amdgcn_mfma_f32_16x16x32_bf16(
              vfp[dt], pfp[nf], Oacc[dt][nf], 0, 0, 0);
#pragma unroll
      for (int nf = 0; nf < 2; ++nf)
        OaccT[nf] = __builtin_amdgcn_mfma_f32_16x16x32_bf16(
            onesf, pfp[nf], OaccT[nf], 0, 0, 0);
      __builtin_amdgcn_s_setprio(0);
      // --- 3. wait for reads; pin QK after the wait (rule #18) ---
      asm volatile("s_waitcnt lgkmcnt(0)" ::: "memory");
      __builtin_amdgcn_sched_barrier(0);
      // --- 4. QK(cur): S^T = K·Q^T for 32 j, base-2 exp, pack bf16 ---
      unsigned pk2[2][2][2];
#pragma unroll
      for (int jj = 0; jj < 2; ++jj) {
#pragma unroll
        for (int nf = 0; nf < 2; ++nf) {
          floatx4 z = (floatx4){0.f, 0.f, 0.f, 0.f};
          z = __builtin_amdgcn_mfma_f32_16x16x32_bf16(kb[jj][0], qa[nf][0], z, 0, 0, 0);
          z = __builtin_amdgcn_mfma_f32_16x16x32_bf16(kb[jj][1], qa[nf][1], z, 0, 0, 0);
          float p0 = __builtin_amdgcn_exp2f(z[0]);
          float p1 = __builtin_amdgcn_exp2f(z[1]);
          float p2 = __builtin_amdgcn_exp2f(z[2]);
          float p3 = __builtin_amdgcn_exp2f(z[3]);
          pk2[jj][nf][0] = pk_bf(p0, p1);
          pk2[jj][nf][1] = pk_bf(p2, p3);
        }
      }
#pragma unroll
      for (int nf = 0; nf < 2; ++nf) {
        union { short8 s; unsigned d[4]; } u;
        u.d[0] = pk2[0][nf][0]; u.d[1] = pk2[0][nf][1];
        u.d[2] = pk2[1][nf][0]; u.d[3] = pk2[1][nf][1];
        pfc[nf] = u.s;
      }
    }
    __syncthreads();
  }

  // ---- final PV: drain the pipeline (prev = last cur = index 1) ----
  __builtin_amdgcn_s_setprio(1);
#pragma unroll
  for (int dt = 0; dt < 4; ++dt)
#pragma unroll
    for (int nf = 0; nf < 2; ++nf)
      Oacc[dt][nf] = __builtin_amdgcn_mfma_f32_16x16x32_bf16(
          vf2[1][dt], pf2[1][nf], Oacc[dt][nf], 0, 0, 0);
#pragma unroll
  for (int nf = 0; nf < 2; ++nf)
    OaccT[nf] = __builtin_amdgcn_mfma_f32_16x16x32_bf16(
        onesf, pf2[1][nf], OaccT[nf], 0, 0, 0);
  __builtin_amdgcn_s_setprio(0);

  // ---- epilogue: denominator straight from ones-MFMA rows (all equal) ----
#pragma unroll
  for (int nf = 0; nf < 2; ++nf) {
    float rinv = 1.f / OaccT[nf][0];
    int n = i0 * 128 + w * 32 + nf * 16 + c;
#pragma unroll
    for (int dt = 0; dt < 4; ++dt) {
      v4u16 pk;
#pragma unroll
      for (int r = 0; r < 4; ++r) pk[r] = f2bf(Oacc[dt][nf][r] * rinv);
      *(v4u16*)(att + ((size_t)b * NSP + n) * C_ + h * 64 + dt * 16 + q * 4) = pk;
    }
  }
}

extern "C" void kernel_launch(void* const* d_in, const int* in_sizes, int n_in,
                              void* d_out, int out_size, void* d_ws, size_t ws_size,
                              hipStream_t stream)
{
  const float* x    = (const float*)d_in[0];
  const float* gw   = (const float*)d_in[1];
  const float* gb   = (const float*)d_in[2];
  const float* qkvw = (const float*)d_in[3];
  const float* qkvb = (const float*)d_in[4];
  const float* pw   = (const float*)d_in[5];
  const float* pb   = (const float*)d_in[6];
  float* out = (float*)d_out;

  u16* xn    = (u16*)d_ws;             // [b][n][c]
  u16* qkb   = xn   + 8388608;         // [b][n][1024]
  u16* vbf   = qkb  + 16777216;        // [b][dd][n'] (k-permuted 64-groups)
  u16* attb  = vbf  + 8388608;         // [b][n][c]
  u16* wq    = attb + 8388608;         // [1536][512]
  u16* wp    = wq   + 786432;          // [512][512]
  float* stats = (float*)(wp + 262144);  // [128][2] fp32

  hipMemsetAsync(stats, 0, 128 * 2 * sizeof(float), stream);
  cvt_bf16<<<1024, 256, 0, stream>>>(qkvw, wq, pw, wp);
  gn_stats<<<1024, 256, 0, stream>>>(x, stats);
  gn_apply<<<2048, 256, 0, stream>>>(x, stats, gw, gb, xn);
  gemm_mfma<0><<<dim3(1536), 256, 0, stream>>>(
      wq, xn, qkvb, nullptr, qkb, vbf, nullptr);
  attn_mfma<<<dim3(1024), 256, 0, stream>>>(qkb, vbf, attb);
  gemm_mfma<1><<<dim3(512), 256, 0, stream>>>(
      wp, attb, pb, x, nullptr, nullptr, out);
}

// Round 8
// 191.278 us; speedup vs baseline: 1.0572x; 1.0363x over previous
//
#include <hip/hip_runtime.h>
#include <math.h>

typedef unsigned short u16;
typedef __attribute__((ext_vector_type(8))) short short8;    // 8 bf16 (4 VGPR)
typedef __attribute__((ext_vector_type(4))) float floatx4;
typedef __attribute__((ext_vector_type(4))) u16 v4u16;
typedef __attribute__((ext_vector_type(8))) u16 v8u16;

#define B_   16
#define C_   512
#define NSP  1024
#define EPSV 1e-5f
#define QSCALE 0.18033688011117f   // 0.125 * log2(e) — softmax in base 2

__device__ __forceinline__ u16 f2bf(float f) {
  union { float f; unsigned u; } v; v.f = f;
  unsigned r = v.u + 0x7FFFu + ((v.u >> 16) & 1u);   // RNE
  return (u16)(r >> 16);
}

__device__ __forceinline__ void gld16(const u16* g, u16* l) {
  __builtin_amdgcn_global_load_lds(
      (const __attribute__((address_space(1))) void*)g,
      (__attribute__((address_space(3))) void*)l, 16, 0, 0);
}

// inline-asm ds_read_b128: invisible to the compiler's alias analysis, so it
// is NOT ordered against outstanding global_load_lds (no implicit vmcnt(0)
// drain). "=&v" early-clobber: destination tuple must not alias any asm
// input address VGPR. Caller must ensure the target buffer has landed
// (explicit vmcnt/barrier protocol) and must follow the group with
// s_waitcnt lgkmcnt(0) + sched_barrier(0) before consuming (rule #18).
__device__ __forceinline__ short8 lds_read_b128(const u16* p) {
  short8 r;
  asm volatile("ds_read_b128 %0, %1"
               : "=&v"(r)
               : "v"((const __attribute__((address_space(3))) u16*)p));
  return r;
}

// pack hi16(a)|hi16(b)<<16 : bf16 truncation pack, 1 instr
__device__ __forceinline__ unsigned pk_bf(float a, float b) {
  return __builtin_amdgcn_perm(__float_as_uint(b), __float_as_uint(a), 0x07060302u);
}

// ------- GroupNorm pass 1 + fp32->bf16 weight cvt, one launch (2048 blk) ---
// blk < 1024: gn_stats partial sums (bg*8 + chunk).
// blk >= 1024: weight conversion (independent work, overlaps stats).
__global__ __launch_bounds__(256) void gn_stats_cvt(
    const float* __restrict__ x, float* __restrict__ stats,
    const float* __restrict__ qa, u16* __restrict__ oa,     // 1536*512
    const float* __restrict__ pa, u16* __restrict__ ob)     // 512*512
{
  int blk = blockIdx.x;
  if (blk >= 1024) {               // ---- cvt path ----
    int cb = blk - 1024;
    const float* in; u16* out; int i;
    if (cb < 768) { in = qa; out = oa; i = (cb * 256 + threadIdx.x) * 4; }
    else          { in = pa; out = ob; i = ((cb - 768) * 256 + threadIdx.x) * 4; }
    float4 v = *(const float4*)(in + i);
    v4u16 o = { f2bf(v.x), f2bf(v.y), f2bf(v.z), f2bf(v.w) };
    *(v4u16*)(out + i) = o;
    return;
  }
  // ---- gn_stats path ----
  int bg = blk >> 3, ck = blk & 7;
  const float4* xp = (const float4*)(x + (((size_t)bg * 64 + ck * 8) * NSP));
  float s = 0.f, ss = 0.f;
#pragma unroll
  for (int it = 0; it < 8; ++it) {
    float4 v = xp[it * 256 + threadIdx.x];
    s  += v.x + v.y + v.z + v.w;
    ss += v.x * v.x + v.y * v.y + v.z * v.z + v.w * v.w;
  }
  for (int off = 32; off > 0; off >>= 1) {
    s  += __shfl_down(s, off);
    ss += __shfl_down(ss, off);
  }
  __shared__ float rs[4], rss[4];
  int lane = threadIdx.x & 63, wv = threadIdx.x >> 6;
  if (lane == 0) { rs[wv] = s; rss[wv] = ss; }
  __syncthreads();
  if (threadIdx.x == 0) {
    float S  = rs[0] + rs[1] + rs[2] + rs[3];
    float SS = rss[0] + rss[1] + rss[2] + rss[3];
    atomicAdd(&stats[bg * 2], S);
    atomicAdd(&stats[bg * 2 + 1], SS);
  }
}

// ------------- GroupNorm pass 2: normalize + transpose to [b][n][c] -------
__global__ __launch_bounds__(256) void gn_apply(
    const float* __restrict__ x, const float* __restrict__ stats,
    const float* __restrict__ gw, const float* __restrict__ gb,
    u16* __restrict__ xn)
{
  int blk = blockIdx.x;            // bg*16 + nt
  int bg = blk >> 4, nt = blk & 15;
  int b = bg >> 3, g = bg & 7;
  float S = stats[bg * 2], SS = stats[bg * 2 + 1];
  float mu  = S * (1.f / 65536.f);
  float var = SS * (1.f / 65536.f) - mu * mu;
  float inv = rsqrtf(var + EPSV);
  __shared__ float T[64][65];
  const float* xb = x + (size_t)bg * 64 * NSP;
  int t = threadIdx.x;
#pragma unroll
  for (int it = 0; it < 4; ++it) {
    int task = it * 256 + t;
    int cc = task >> 4, ns = task & 15;
    float4 v = *(const float4*)(xb + (size_t)cc * NSP + nt * 64 + ns * 4);
    T[cc][ns * 4 + 0] = v.x; T[cc][ns * 4 + 1] = v.y;
    T[cc][ns * 4 + 2] = v.z; T[cc][ns * 4 + 3] = v.w;
  }
  __syncthreads();
#pragma unroll
  for (int it = 0; it < 2; ++it) {
    int task = it * 256 + t;
    int n = task >> 3, cs = task & 7;
    v8u16 o;
#pragma unroll
    for (int u = 0; u < 8; ++u) {
      int cg = g * 64 + cs * 8 + u;
      float val = (T[cs * 8 + u][n] - mu) * inv * gw[cg] + gb[cg];
      o[u] = f2bf(val);
    }
    *(v8u16*)(xn + ((size_t)b * NSP + nt * 64 + n) * C_ + g * 64 + cs * 8) = o;
  }
}

// ---- bf16 MFMA GEMM: C[b][m][n] = W[m][k] * X[b][n][k]^T + bias[m] ----
// Flat 1D grid, id = y*128 + b*8 + x -> m-tiles sharing an X-panel share id%8
// (same XCD -> B-panel L2-resident).
// v9 (validated R5): 3-stage counted-vmcnt pipeline + inline-asm
// ds_read_b128 frag loads (bypasses compiler's conservative vmcnt(0) drain
// after global_load_lds issue). Correctness held by explicit vmcnt(4)+
// s_barrier protocol; lgkmcnt(0)+sched_barrier(0) before MFMA (rule #18).
// MODE 0 (qkv): m<1024 -> out_qk[b][n][m] bf16 (Q rows scaled by QSCALE);
//               m>=1024 -> out_v[b][m-1024][n'] bf16, n' k-PERMUTED within
//               each 64-col group (k = (j&0x23)|((j&0x0C)<<1)|((j&0x10)>>2))
//               so attn PV A-frags are single ds_read_b128.
// MODE 1 (proj): out_f[b][m][n] fp32 = acc + bias + resid.
template <int MODE>
__global__ __launch_bounds__(256) void gemm_mfma(
    const u16* __restrict__ W, const u16* __restrict__ X,
    const float* __restrict__ bias, const float* __restrict__ resid,
    u16* __restrict__ out_qk, u16* __restrict__ out_v,
    float* __restrict__ out_f)
{
  __shared__ u16 smem[24576];      // 3 x 16KB stage buffers; epilogue overlays
  int id = blockIdx.x;
  int yb = id >> 7, rr = id & 127;
  int b = rr >> 3, xb_ = rr & 7;
  int m0 = yb * 128, n0 = xb_ * 128;
  int t = threadIdx.x, lane = t & 63, w = t >> 6;
  int c = lane & 15, q = lane >> 4;
  int wm = w >> 1, wn = w & 1;
  const u16* Xb = X + (size_t)b * NSP * C_;

  floatx4 acc[4][4];
#pragma unroll
  for (int mi = 0; mi < 4; ++mi)
#pragma unroll
    for (int ni = 0; ni < 4; ++ni) acc[mi][ni] = (floatx4){0.f, 0.f, 0.f, 0.f};

  auto stage = [&](int buf, int k0) {
    u16* Asb = smem + buf * 8192;
    u16* Bsb = Asb + 4096;
#pragma unroll
    for (int it = 0; it < 2; ++it) {
      int task = it * 256 + t;
      int mr = task >> 2;
      int gk = (task & 3) ^ ((mr >> 1) & 3);
      gld16(W + (size_t)(m0 + mr) * C_ + k0 + gk * 8, Asb + task * 8);
    }
#pragma unroll
    for (int it = 0; it < 2; ++it) {
      int task = it * 256 + t;
      int nr = task >> 2;
      int gk = (task & 3) ^ ((nr >> 1) & 3);
      gld16(Xb + (size_t)(n0 + nr) * C_ + k0 + gk * 8, Bsb + task * 8);
    }
  };

  auto compute = [&](int buf) {
    const u16* As = smem + buf * 8192;
    const u16* Bs = As + 4096;
    short8 af[4], bfr[4];
#pragma unroll
    for (int mi = 0; mi < 4; ++mi) {
      int m = wm * 64 + mi * 16 + c;
      af[mi] = lds_read_b128(As + m * 32 + ((q ^ ((m >> 1) & 3)) << 3));
    }
#pragma unroll
    for (int ni = 0; ni < 4; ++ni) {
      int n = wn * 64 + ni * 16 + c;
      bfr[ni] = lds_read_b128(Bs + n * 32 + ((q ^ ((n >> 1) & 3)) << 3));
    }
    asm volatile("s_waitcnt lgkmcnt(0)" ::: "memory");
    __builtin_amdgcn_sched_barrier(0);
#pragma unroll
    for (int mi = 0; mi < 4; ++mi)
#pragma unroll
      for (int ni = 0; ni < 4; ++ni)
        acc[mi][ni] = __builtin_amdgcn_mfma_f32_16x16x32_bf16(
            af[mi], bfr[ni], acc[mi][ni], 0, 0, 0);
  };

  stage(0, 0);
  stage(1, 32);
  int cur = 0, tgt = 2;
  for (int ki = 0; ki < 14; ++ki) {
    asm volatile("s_waitcnt vmcnt(4)" ::: "memory");
    __builtin_amdgcn_s_barrier();
    stage(tgt, (ki + 2) * 32);
    compute(cur);
    cur = (cur == 2) ? 0 : cur + 1;
    tgt = (tgt == 2) ? 0 : tgt + 1;
  }
  asm volatile("s_waitcnt vmcnt(4)" ::: "memory");
  __builtin_amdgcn_s_barrier();
  compute(2);                      // ki=14 -> buf 14%3 = 2
  asm volatile("s_waitcnt vmcnt(0)" ::: "memory");
  __builtin_amdgcn_s_barrier();
  compute(0);                      // ki=15 -> buf 15%3 = 0
  __syncthreads();                 // all waves out of buf0 before Cl overlay

  if (MODE == 0) {
    if (m0 < 1024) {       // Q/K region: transpose to [n][m] via LDS
      float sc = (m0 < 512) ? QSCALE : 1.0f;
      u16* Cl = smem;      // [128 n][136 m-stride]
#pragma unroll
      for (int mi = 0; mi < 4; ++mi) {
        floatx4 bi = *(const floatx4*)(bias + m0 + wm * 64 + mi * 16 + q * 4);
#pragma unroll
        for (int ni = 0; ni < 4; ++ni) {
          int n = wn * 64 + ni * 16 + c;
          int m = wm * 64 + mi * 16 + q * 4;
          v4u16 pk;
#pragma unroll
          for (int r = 0; r < 4; ++r) pk[r] = f2bf((acc[mi][ni][r] + bi[r]) * sc);
          *(v4u16*)(Cl + n * 136 + m) = pk;
        }
      }
      __syncthreads();
#pragma unroll
      for (int it = 0; it < 8; ++it) {
        int task = it * 256 + t;
        int n = task >> 4, seg = task & 15;
        v8u16 v = *(const v8u16*)(Cl + n * 136 + seg * 8);
        *(v8u16*)(out_qk + ((size_t)b * NSP + n0 + n) * 1024 + m0 + seg * 8) = v;
      }
    } else {               // V region: [m][n'] via LDS transpose, k-permuted
      u16* Cl = smem;      // [128 m][136 n-stride]
#pragma unroll
      for (int mi = 0; mi < 4; ++mi) {
        floatx4 bi = *(const floatx4*)(bias + m0 + wm * 64 + mi * 16 + q * 4);
#pragma unroll
        for (int ni = 0; ni < 4; ++ni) {
          int n = wn * 64 + ni * 16 + c;
          int m = wm * 64 + mi * 16 + q * 4;
#pragma unroll
          for (int r = 0; r < 4; ++r)
            Cl[(m + r) * 136 + n] = f2bf(acc[mi][ni][r] + bi[r]);
        }
      }
      __syncthreads();
      // store with per-64-group column permutation j -> k:
      // k = (j&0x23) | ((j&0x0C)<<1) | ((j&0x10)>>2).
      // source octet seg*8..+7 maps to two 4-runs at k0 and k0+8,
      // k0 = ((s&4)<<3) | ((s&1)<<4) | ((s&2)<<1), s = seg&7.
#pragma unroll
      for (int it = 0; it < 8; ++it) {
        int task = it * 256 + t;
        int m = task >> 4, seg = task & 15;
        int g64 = seg >> 3, s = seg & 7;
        int k0 = ((s & 4) << 3) | ((s & 1) << 4) | ((s & 2) << 1);
        v8u16 v = *(const v8u16*)(Cl + m * 136 + seg * 8);
        v4u16 lo = { v[0], v[1], v[2], v[3] };
        v4u16 hi = { v[4], v[5], v[6], v[7] };
        size_t base = ((size_t)b * C_ + m0 - 1024 + m) * NSP + n0 + g64 * 64;
        *(v4u16*)(out_v + base + k0) = lo;
        *(v4u16*)(out_v + base + k0 + 8) = hi;
      }
    }
  } else {                 // proj: fp32 [m][n] + bias + residual
#pragma unroll
    for (int mi = 0; mi < 4; ++mi) {
      floatx4 bi = *(const floatx4*)(bias + m0 + wm * 64 + mi * 16 + q * 4);
#pragma unroll
      for (int ni = 0; ni < 4; ++ni) {
        int n = n0 + wn * 64 + ni * 16 + c;
        int m = m0 + wm * 64 + mi * 16 + q * 4;
#pragma unroll
        for (int r = 0; r < 4; ++r) {
          size_t o = ((size_t)b * C_ + m + r) * NSP + n;
          out_f[o] = acc[mi][ni][r] + bi[r] + resid[o];
        }
      }
    }
  }
}

// ---- flash attention v10: R5 v7 structure + counted-vmcnt barriers (T4) ----
// R7 ledger: interleave ✓, asm-dedrain ✓(gemm), 8-wave ✗, T15 ✗. v10 keeps
// the proven 4-wave v7 body and ONLY changes the loop barrier protocol:
// old: __syncthreads per j0 = s_waitcnt vmcnt(0) lgkmcnt(0) + s_barrier —
//      drains the prefetch issued THIS iteration (~1 j0 body to cover up to
//      ~900cy HBM latency; residue stalls every wave at the barrier).
// new: issue prefetch -> s_waitcnt vmcnt(4) (waits only the PREVIOUS iter's
//      4 loads; this iter's 4 stay in flight across the barrier) -> compute
//      -> raw s_barrier (no drain). Tail j0=15: no prefetch -> vmcnt(0).
// Race audit: barrier still separates all parity-p ds_reads from the j0+1
// prefetch overwriting parity p (WAR ok); vmcnt-before-reads guarantees
// parity-p data landed (RAW ok); loop is wave-uniform (no divergent barrier).
// LDS 32KB: Q [0..8192) (dead after frag load -> odd-parity K/V buffer),
// even-parity K/V at [8192..16384). Softmax base-2 (Q pre-scaled in gemm0).
// Denominator via mfma(ones, P). V k-permuted by gemm0 -> single b128 frag.
__global__ __launch_bounds__(256, 4) void attn_mfma(
    const u16* __restrict__ qk, const u16* __restrict__ vbuf,
    u16* __restrict__ att)
{
  __shared__ u16 __align__(16) smem[16384];   // 32 KB
  int id = blockIdx.x;
  int hb = id & 127;
  int i0 = id >> 7;
  int h = hb >> 4, b = hb & 15;
  int t = threadIdx.x, lane = t & 63, w = t >> 6;
  int c = lane & 15, q = lane >> 4;
  const u16* qbase = qk + (size_t)b * NSP * 1024;
  const u16* vbase = vbuf + (size_t)(b * C_ + h * 64) * NSP;

  // stage Q(128x64) -> [0..8192); K0 -> [8192..12288); V0 -> [12288..16384)
#pragma unroll
  for (int it = 0; it < 4; ++it) {
    int task = it * 256 + t;
    int r = task >> 3, seg = task & 7, ds = (seg ^ (r & 7)) * 8;
    gld16(qbase + (size_t)(i0 * 128 + r) * 1024 + h * 64 + ds, smem + task * 8);
  }
#pragma unroll
  for (int it = 0; it < 2; ++it) {
    int task = it * 256 + t;
    int r = task >> 3, seg = task & 7, ds = (seg ^ (r & 7)) * 8;
    gld16(qbase + (size_t)r * 1024 + 512 + h * 64 + ds, smem + 8192 + task * 8);
    gld16(vbase + (size_t)r * NSP + ds, smem + 12288 + task * 8);
  }
  __syncthreads();

  short8 qa[2][2];                 // rows w*32 + nf*16 + c
#pragma unroll
  for (int nf = 0; nf < 2; ++nf) {
    int row = w * 32 + nf * 16 + c;
#pragma unroll
    for (int ch = 0; ch < 2; ++ch)
      qa[nf][ch] = *(const short8*)(smem + row * 64 + (((q + 4 * ch) ^ (c & 7)) << 3));
  }
  __syncthreads();                 // all waves done reading Q before overlay

  short8 onesf;                    // all-ones bf16 A-operand (1.0 = 0x3F80)
#pragma unroll
  for (int u = 0; u < 8; ++u) onesf[u] = (short)0x3F80;

  floatx4 Oacc[4][2];              // [dt][nf]
  floatx4 OaccT[2];                // ones-MFMA column sums -> denominator
#pragma unroll
  for (int dt = 0; dt < 4; ++dt)
#pragma unroll
    for (int nf = 0; nf < 2; ++nf) Oacc[dt][nf] = (floatx4){0.f, 0.f, 0.f, 0.f};
#pragma unroll
  for (int nf = 0; nf < 2; ++nf) OaccT[nf] = (floatx4){0.f, 0.f, 0.f, 0.f};

  for (int j0 = 0; j0 < 16; ++j0) {
    int p = j0 & 1;
    u16* KS = smem + (p ? 0 : 8192);
    u16* VS = KS + 4096;
    if (j0 < 15) {                 // prefetch next K/V into the other parity
      u16* KN = smem + (p ? 8192 : 0);
      u16* VN = KN + 4096;
#pragma unroll
      for (int it = 0; it < 2; ++it) {
        int task = it * 256 + t;
        int r = task >> 3, seg = task & 7, ds = (seg ^ (r & 7)) * 8;
        gld16(qbase + (size_t)((j0 + 1) * 64 + r) * 1024 + 512 + h * 64 + ds,
              KN + task * 8);
        gld16(vbase + (size_t)r * NSP + (j0 + 1) * 64 + ds, VN + task * 8);
      }
      // wait ONLY for the previous iteration's 4 loads (parity p data);
      // this iteration's 4 prefetch loads stay in flight across the barrier.
      asm volatile("s_waitcnt vmcnt(4)" ::: "memory");
    } else {
      asm volatile("s_waitcnt vmcnt(0)" ::: "memory");   // tail: drain last
    }
    __builtin_amdgcn_sched_barrier(0);
#pragma unroll
    for (int jt2 = 0; jt2 < 2; ++jt2) {
      // --- batched asm frag reads: 4x K + 4x V, one lgkm wait ---
      short8 kb[2][2], vf[4];
#pragma unroll
      for (int jj = 0; jj < 2; ++jj) {
        int row = (jt2 * 2 + jj) * 16 + c;
        kb[jj][0] = lds_read_b128(KS + row * 64 + ((q ^ (row & 7)) << 3));
        kb[jj][1] = lds_read_b128(KS + row * 64 + (((q + 4) ^ (row & 7)) << 3));
      }
#pragma unroll
      for (int dt = 0; dt < 4; ++dt) {
        int dd = dt * 16 + c;
        vf[dt] = lds_read_b128(VS + dd * 64 + (((jt2 * 4 + q) ^ (dd & 7)) << 3));
      }
      asm volatile("s_waitcnt lgkmcnt(0)" ::: "memory");
      __builtin_amdgcn_sched_barrier(0);
      // --- QK half: S^T = K·Q^T for 32 j, base-2 exp, pack P bf16 ---
      unsigned pk2[2][2][2];
#pragma unroll
      for (int jj = 0; jj < 2; ++jj) {
#pragma unroll
        for (int nf = 0; nf < 2; ++nf) {
          floatx4 z = (floatx4){0.f, 0.f, 0.f, 0.f};
          z = __builtin_amdgcn_mfma_f32_16x16x32_bf16(kb[jj][0], qa[nf][0], z, 0, 0, 0);
          z = __builtin_amdgcn_mfma_f32_16x16x32_bf16(kb[jj][1], qa[nf][1], z, 0, 0, 0);
          float p0 = __builtin_amdgcn_exp2f(z[0]);
          float p1 = __builtin_amdgcn_exp2f(z[1]);
          float p2 = __builtin_amdgcn_exp2f(z[2]);
          float p3 = __builtin_amdgcn_exp2f(z[3]);
          pk2[jj][nf][0] = pk_bf(p0, p1);
          pk2[jj][nf][1] = pk_bf(p2, p3);
        }
      }
      short8 pf[2];
#pragma unroll
      for (int nf = 0; nf < 2; ++nf) {
        union { short8 s; unsigned d[4]; } u;
        u.d[0] = pk2[0][nf][0]; u.d[1] = pk2[0][nf][1];
        u.d[2] = pk2[1][nf][0]; u.d[3] = pk2[1][nf][1];
        pf[nf] = u.s;
      }
      // --- PV half: k-permuted V, all operands already in regs ---
      __builtin_amdgcn_s_setprio(1);
#pragma unroll
      for (int dt = 0; dt < 4; ++dt)
#pragma unroll
        for (int nf = 0; nf < 2; ++nf)
          Oacc[dt][nf] = __builtin_amdgcn_mfma_f32_16x16x32_bf16(
              vf[dt], pf[nf], Oacc[dt][nf], 0, 0, 0);
#pragma unroll
      for (int nf = 0; nf < 2; ++nf)
        OaccT[nf] = __builtin_amdgcn_mfma_f32_16x16x32_bf16(
            onesf, pf[nf], OaccT[nf], 0, 0, 0);
      __builtin_amdgcn_s_setprio(0);
    }
    __builtin_amdgcn_s_barrier();  // raw barrier: NO vmcnt drain (T4)
  }

  // ---- epilogue: denominator straight from ones-MFMA rows (all equal) ----
#pragma unroll
  for (int nf = 0; nf < 2; ++nf) {
    float rinv = 1.f / OaccT[nf][0];
    int n = i0 * 128 + w * 32 + nf * 16 + c;
#pragma unroll
    for (int dt = 0; dt < 4; ++dt) {
      v4u16 pk;
#pragma unroll
      for (int r = 0; r < 4; ++r) pk[r] = f2bf(Oacc[dt][nf][r] * rinv);
      *(v4u16*)(att + ((size_t)b * NSP + n) * C_ + h * 64 + dt * 16 + q * 4) = pk;
    }
  }
}

extern "C" void kernel_launch(void* const* d_in, const int* in_sizes, int n_in,
                              void* d_out, int out_size, void* d_ws, size_t ws_size,
                              hipStream_t stream)
{
  const float* x    = (const float*)d_in[0];
  const float* gw   = (const float*)d_in[1];
  const float* gb   = (const float*)d_in[2];
  const float* qkvw = (const float*)d_in[3];
  const float* qkvb = (const float*)d_in[4];
  const float* pw   = (const float*)d_in[5];
  const float* pb   = (const float*)d_in[6];
  float* out = (float*)d_out;

  u16* xn    = (u16*)d_ws;             // [b][n][c]
  u16* qkb   = xn   + 8388608;         // [b][n][1024]
  u16* vbf   = qkb  + 16777216;        // [b][dd][n'] (k-permuted 64-groups)
  u16* attb  = vbf  + 8388608;         // [b][n][c]
  u16* wq    = attb + 8388608;         // [1536][512]
  u16* wp    = wq   + 786432;          // [512][512]
  float* stats = (float*)(wp + 262144);  // [128][2] fp32

  hipMemsetAsync(stats, 0, 128 * 2 * sizeof(float), stream);
  gn_stats_cvt<<<2048, 256, 0, stream>>>(x, stats, qkvw, wq, pw, wp);
  gn_apply<<<2048, 256, 0, stream>>>(x, stats, gw, gb, xn);
  gemm_mfma<0><<<dim3(1536), 256, 0, stream>>>(
      wq, xn, qkvb, nullptr, qkb, vbf, nullptr);
  attn_mfma<<<dim3(1024), 256, 0, stream>>>(qkb, vbf, attb);
  gemm_mfma<1><<<dim3(512), 256, 0, stream>>>(
      wp, attb, pb, x, nullptr, nullptr, out);
}